// Round 15
// baseline (99.001 us; speedup 1.0000x reference)
//
#include <hip/hip_runtime.h>
#include <hip/hip_bf16.h>

#define NL  128   // layers (n)
#define DK  256   // d_in (k)
#define DO_ 256   // d_out (o)
#define MB  1024  // batch (m)

typedef __attribute__((ext_vector_type(4))) float f32x4;
typedef __attribute__((ext_vector_type(8))) short bf16x8;
typedef __attribute__((ext_vector_type(8))) unsigned short u16x8;
typedef __attribute__((ext_vector_type(4))) unsigned short u16x4;

static __device__ __forceinline__ unsigned short f2bf(float f) {
  __hip_bfloat16 h = __float2bfloat16(f);
  return __builtin_bit_cast(unsigned short, h);
}

// ---------------------------------------------------------------------------
// Prep: W[n][k][o] fp32 -> Wt in MFMA B-fragment order, bf16 (verified R4-R14):
//   unit (o, kc[8-k chunk]) -> ob=o>>4, lrow=o&15, s=kc>>2, lhi=kc&3
//   elem offset = ((n*16+ob)*8 + s)*512 + (lhi*16+lrow)*8 + (k&7)
// so a wave's B-load for (ob, s) is ONE contiguous 1KB dwordx4 per lane.
// ---------------------------------------------------------------------------
__global__ __launch_bounds__(256) void wt_prep(const float* __restrict__ W,
                                               unsigned short* __restrict__ Wt) {
  const int n     = blockIdx.y;
  const int ktile = (blockIdx.x >> 2) * 64;
  const int otile = (blockIdx.x & 3) * 64;
  __shared__ float tile[64][65];  // +1 pad: conflict-free column reads
  const float* Wn = W + (size_t)n * DK * DO_;
  const int t  = threadIdx.x;
  const int lr = t >> 4;
  const int lc = (t & 15) * 4;
#pragma unroll
  for (int p = 0; p < 4; ++p) {
    const int k = p * 16 + lr;
    const float4 v = *(const float4*)(Wn + (size_t)(ktile + k) * DO_ + otile + lc);
    tile[k][lc + 0] = v.x; tile[k][lc + 1] = v.y;
    tile[k][lc + 2] = v.z; tile[k][lc + 3] = v.w;
  }
  __syncthreads();
  const int ol = t >> 2;            // local o 0..63
  const int o  = otile + ol;
  const int kq = t & 3;
  unsigned short* Wt_n = Wt + (size_t)n * DO_ * DK;
#pragma unroll
  for (int h = 0; h < 2; ++h) {
    u16x8 w;
#pragma unroll
    for (int j = 0; j < 8; ++j) w[j] = f2bf(tile[kq * 16 + h * 8 + j][ol]);
    const int kc = (ktile >> 3) + kq * 2 + h;   // global 8-k chunk id (0..31)
    const int ob = o >> 4, lrw = o & 15, s = kc >> 2, lh = kc & 3;
    *(u16x8*)(Wt_n + ((size_t)(ob * 8 + s) * 64 + lh * 16 + lrw) * 8) = w;
  }
}

// ---------------------------------------------------------------------------
// Main: EXACT R14 (best: 72.0 us) with ONE change — __launch_bounds__(512,8):
// 4 co-resident blocks/CU (was 2). VGPR 44 fits the 64-cap; LDS 4x32=128KB.
// Doubles per-CU HBM duty cycle (more independent stage/store bursts in
// flight). Everything else byte-identical to R14.
// ---------------------------------------------------------------------------
__global__ __launch_bounds__(512, 8) void nlinear_mfma(
    const float* __restrict__ X, const unsigned short* __restrict__ Wt,
    const float* __restrict__ bias, float* __restrict__ out) {
  const int wid  = blockIdx.x;
  const int n    = (wid & 7) * 16 + ((wid >> 3) & 15);
  const int mg   = wid >> 7;          // 0..15, 64 rows each
  const int t    = threadIdx.x;
  const int wave = t >> 6;            // 0..7 = o-slice of 32
  const int lane = t & 63;
  const int lrow = lane & 15;
  const int lhi  = lane >> 4;
  const int mbase = mg * 64;

  __shared__ unsigned short Alds[64 * 256];  // 32 KB; A-tile, then epilogue tile

  // ---- stage: wave w loads rows w*8+j (j=0..7), lane takes k=lane*4 ----
  const float* xw = X + ((size_t)(mbase + wave * 8) * NL + n) * DK + lane * 4;
  f32x4 xv[8];
#pragma unroll
  for (int j = 0; j < 8; ++j)
    xv[j] = *(const f32x4*)(xw + (size_t)j * NL * DK);

  // bias: issue early, independent of everything
  const float* bb = bias + n * DO_ + wave * 32 + lhi * 4;
  f32x4 bv[2];
#pragma unroll
  for (int oj = 0; oj < 2; ++oj) bv[oj] = *(const f32x4*)(bb + oj * 16);

  char* ab = (char*)Alds;
#pragma unroll
  for (int j = 0; j < 8; ++j) {
    u16x4 h;
#pragma unroll
    for (int e = 0; e < 4; ++e) h[e] = f2bf(xv[j][e]);
    // row = wave*8+j; chunk c = lane>>1; slot = c ^ (row&7) = c ^ j  (verified)
    *(u16x4*)(ab + (wave * 8 + j) * 512 + (((lane >> 1) ^ j) << 4) + (lane & 1) * 8) = h;
  }
  __syncthreads();  // staging barrier

  const unsigned short* Wn = Wt + (size_t)n * DO_ * DK;

  f32x4 acc[4][2];
#pragma unroll
  for (int mt = 0; mt < 4; ++mt)
#pragma unroll
    for (int oj = 0; oj < 2; ++oj) acc[mt][oj] = (f32x4){0.f, 0.f, 0.f, 0.f};

  // B-load helper: coalesced 1KB per instr from prefragmented, L2-resident Wt
#define BLOAD(s, oj) \
  (*(const bf16x8*)(Wn + ((size_t)(((wave * 2 + (oj)) * 8) + (s)) * 64 + lane) * 8))

  // 2-deep explicit B prefetch pipeline (all indices compile-time: no scratch)
  bf16x8 bA0 = BLOAD(0, 0), bA1 = BLOAD(0, 1);
  bf16x8 bB0 = BLOAD(1, 0), bB1 = BLOAD(1, 1);

#pragma unroll
  for (int s = 0; s < 8; ++s) {
    const bf16x8 bc0 = (s & 1) ? bB0 : bA0;
    const bf16x8 bc1 = (s & 1) ? bB1 : bA1;
    if (s < 6) {  // refill the slot just consumed with s+2
      if (s & 1) { bB0 = BLOAD(s + 2, 0); bB1 = BLOAD(s + 2, 1); }
      else       { bA0 = BLOAD(s + 2, 0); bA1 = BLOAD(s + 2, 1); }
    }
    bf16x8 af[4];
#pragma unroll
    for (int mt = 0; mt < 4; ++mt) {
      const int row = mt * 16 + lrow;
      af[mt] = *(const bf16x8*)(ab + row * 512 + (((s * 4 + lhi) ^ (row & 7)) << 4));
    }
#pragma unroll
    for (int mt = 0; mt < 4; ++mt) {  // SWAPPED: D[o][m], lane regs = 4 contig o
      acc[mt][0] = __builtin_amdgcn_mfma_f32_16x16x32_bf16(bc0, af[mt], acc[mt][0], 0, 0, 0);
      acc[mt][1] = __builtin_amdgcn_mfma_f32_16x16x32_bf16(bc1, af[mt], acc[mt][1], 0, 0, 0);
    }
  }
#undef BLOAD

  // ---- LDS-bounce epilogue: 2 passes x 32 rows (reuses the 32KB A-LDS) ----
  // Write: acc[mt][oj]+bv at [rloc][c16 = wave*8+oj*4+lhi], slot c^(rloc&7)
  //        (8-beat optimal). Read: lane takes chunk lane^(rloc&7)
  //        (conflict-free permutation) -> ONE contiguous 1KB NT store/row.
#pragma unroll
  for (int pass = 0; pass < 2; ++pass) {
    asm volatile("s_waitcnt lgkmcnt(0)" ::: "memory");
    __builtin_amdgcn_s_barrier();
#pragma unroll
    for (int mt2 = 0; mt2 < 2; ++mt2) {
      const int mtg  = pass * 2 + mt2;
      const int rloc = mt2 * 16 + lrow;          // 0..31
#pragma unroll
      for (int oj = 0; oj < 2; ++oj) {
        const f32x4 v = acc[mtg][oj] + bv[oj];
        const int c = wave * 8 + oj * 4 + lhi;   // 16B chunk index 0..63
        *(f32x4*)(ab + rloc * 1024 + ((c ^ (rloc & 7)) << 4)) = v;
      }
    }
    asm volatile("s_waitcnt lgkmcnt(0)" ::: "memory");
    __builtin_amdgcn_s_barrier();
    // read + NT store: wave handles rows wave*4 .. +4 of this pass
#pragma unroll
    for (int j = 0; j < 4; ++j) {
      const int rloc = wave * 4 + j;
      const int m    = mbase + pass * 32 + rloc;
      const f32x4 v  = *(const f32x4*)(ab + rloc * 1024 + ((lane ^ (rloc & 7)) << 4));
      __builtin_nontemporal_store(
          v, (f32x4*)(out + ((size_t)m * NL + n) * DO_ + lane * 4));
    }
  }
}

// ---------------------------------------------------------------------------
// Fallback (only if ws too small for Wt): plain fp32, correct but slow.
// ---------------------------------------------------------------------------
__global__ __launch_bounds__(256) void nlinear_naive(
    const float* __restrict__ X, const float* __restrict__ W,
    const float* __restrict__ B, float* __restrict__ out) {
  const int n = blockIdx.y;
  const int m = blockIdx.x;
  const int o = threadIdx.x;
  __shared__ float xs[DK];
  xs[o] = X[((size_t)m * NL + n) * DK + o];
  __syncthreads();
  const float* Wn = W + (size_t)n * DK * DO_;
  float s = B[n * DO_ + o];
  for (int k = 0; k < DK; ++k) s = fmaf(xs[k], Wn[(size_t)k * DO_ + o], s);
  out[((size_t)m * NL + n) * DO_ + o] = s;
}

extern "C" void kernel_launch(void* const* d_in, const int* in_sizes, int n_in,
                              void* d_out, int out_size, void* d_ws, size_t ws_size,
                              hipStream_t stream) {
  const float* x = (const float*)d_in[0];
  const float* w = (const float*)d_in[1];
  const float* b = (const float*)d_in[2];
  float* out     = (float*)d_out;
  const size_t wt_bytes = (size_t)NL * DK * DO_ * sizeof(unsigned short);
  if (ws_size >= wt_bytes) {
    unsigned short* wt = (unsigned short*)d_ws;
    wt_prep<<<dim3(16, NL), 256, 0, stream>>>(w, wt);
    nlinear_mfma<<<dim3(2048), 512, 0, stream>>>(x, wt, b, out);
  } else {
    nlinear_naive<<<dim3(MB, NL), 256, 0, stream>>>(x, w, b, out);
  }
}

// Round 16
// 70.197 us; speedup vs baseline: 1.4103x; 1.4103x over previous
//
#include <hip/hip_runtime.h>
#include <hip/hip_bf16.h>

#define NL  128   // layers (n)
#define DK  256   // d_in (k)
#define DO_ 256   // d_out (o)
#define MB  1024  // batch (m)

typedef __attribute__((ext_vector_type(4))) float f32x4;
typedef __attribute__((ext_vector_type(8))) short bf16x8;
typedef __attribute__((ext_vector_type(8))) unsigned short u16x8;
typedef __attribute__((ext_vector_type(4))) unsigned short u16x4;

static __device__ __forceinline__ unsigned short f2bf(float f) {
  __hip_bfloat16 h = __float2bfloat16(f);
  return __builtin_bit_cast(unsigned short, h);
}

// ---------------------------------------------------------------------------
// Prep: W[n][k][o] fp32 -> Wt in MFMA B-fragment order, bf16 (verified R4-R15):
//   unit (o, kc[8-k chunk]) -> ob=o>>4, lrow=o&15, s=kc>>2, lhi=kc&3
//   elem offset = ((n*16+ob)*8 + s)*512 + (lhi*16+lrow)*8 + (k&7)
// so a wave's B-load for (ob, s) is ONE contiguous 1KB dwordx4 per lane.
// ---------------------------------------------------------------------------
__global__ __launch_bounds__(256) void wt_prep(const float* __restrict__ W,
                                               unsigned short* __restrict__ Wt) {
  const int n     = blockIdx.y;
  const int ktile = (blockIdx.x >> 2) * 64;
  const int otile = (blockIdx.x & 3) * 64;
  __shared__ float tile[64][65];  // +1 pad: conflict-free column reads
  const float* Wn = W + (size_t)n * DK * DO_;
  const int t  = threadIdx.x;
  const int lr = t >> 4;
  const int lc = (t & 15) * 4;
#pragma unroll
  for (int p = 0; p < 4; ++p) {
    const int k = p * 16 + lr;
    const float4 v = *(const float4*)(Wn + (size_t)(ktile + k) * DO_ + otile + lc);
    tile[k][lc + 0] = v.x; tile[k][lc + 1] = v.y;
    tile[k][lc + 2] = v.z; tile[k][lc + 3] = v.w;
  }
  __syncthreads();
  const int ol = t >> 2;            // local o 0..63
  const int o  = otile + ol;
  const int kq = t & 3;
  unsigned short* Wt_n = Wt + (size_t)n * DO_ * DK;
#pragma unroll
  for (int h = 0; h < 2; ++h) {
    u16x8 w;
#pragma unroll
    for (int j = 0; j < 8; ++j) w[j] = f2bf(tile[kq * 16 + h * 8 + j][ol]);
    const int kc = (ktile >> 3) + kq * 2 + h;   // global 8-k chunk id (0..31)
    const int ob = o >> 4, lrw = o & 15, s = kc >> 2, lh = kc & 3;
    *(u16x8*)(Wt_n + ((size_t)(ob * 8 + s) * 64 + lh * 16 + lrw) * 8) = w;
  }
}

// ---------------------------------------------------------------------------
// Main: EXACT R14 (best: 72.0 us) with ONE change — __launch_bounds__(512,6):
// 3 co-resident blocks/CU (R14: 2; R15's (512,8) spilled at VGPR 32).
// VGPR cap ~85 fits the kernel's 44 with zero spill; LDS 3x32=96KB <= 160.
// Everything else byte-identical to R14.
// ---------------------------------------------------------------------------
__global__ __launch_bounds__(512, 6) void nlinear_mfma(
    const float* __restrict__ X, const unsigned short* __restrict__ Wt,
    const float* __restrict__ bias, float* __restrict__ out) {
  const int wid  = blockIdx.x;
  const int n    = (wid & 7) * 16 + ((wid >> 3) & 15);
  const int mg   = wid >> 7;          // 0..15, 64 rows each
  const int t    = threadIdx.x;
  const int wave = t >> 6;            // 0..7 = o-slice of 32
  const int lane = t & 63;
  const int lrow = lane & 15;
  const int lhi  = lane >> 4;
  const int mbase = mg * 64;

  __shared__ unsigned short Alds[64 * 256];  // 32 KB; A-tile, then epilogue tile

  // ---- stage: wave w loads rows w*8+j (j=0..7), lane takes k=lane*4 ----
  const float* xw = X + ((size_t)(mbase + wave * 8) * NL + n) * DK + lane * 4;
  f32x4 xv[8];
#pragma unroll
  for (int j = 0; j < 8; ++j)
    xv[j] = *(const f32x4*)(xw + (size_t)j * NL * DK);

  // bias: issue early, independent of everything
  const float* bb = bias + n * DO_ + wave * 32 + lhi * 4;
  f32x4 bv[2];
#pragma unroll
  for (int oj = 0; oj < 2; ++oj) bv[oj] = *(const f32x4*)(bb + oj * 16);

  char* ab = (char*)Alds;
#pragma unroll
  for (int j = 0; j < 8; ++j) {
    u16x4 h;
#pragma unroll
    for (int e = 0; e < 4; ++e) h[e] = f2bf(xv[j][e]);
    // row = wave*8+j; chunk c = lane>>1; slot = c ^ (row&7) = c ^ j  (verified)
    *(u16x4*)(ab + (wave * 8 + j) * 512 + (((lane >> 1) ^ j) << 4) + (lane & 1) * 8) = h;
  }
  __syncthreads();  // staging barrier

  const unsigned short* Wn = Wt + (size_t)n * DO_ * DK;

  f32x4 acc[4][2];
#pragma unroll
  for (int mt = 0; mt < 4; ++mt)
#pragma unroll
    for (int oj = 0; oj < 2; ++oj) acc[mt][oj] = (f32x4){0.f, 0.f, 0.f, 0.f};

  // B-load helper: coalesced 1KB per instr from prefragmented, L2-resident Wt
#define BLOAD(s, oj) \
  (*(const bf16x8*)(Wn + ((size_t)(((wave * 2 + (oj)) * 8) + (s)) * 64 + lane) * 8))

  // 2-deep explicit B prefetch pipeline (all indices compile-time: no scratch)
  bf16x8 bA0 = BLOAD(0, 0), bA1 = BLOAD(0, 1);
  bf16x8 bB0 = BLOAD(1, 0), bB1 = BLOAD(1, 1);

#pragma unroll
  for (int s = 0; s < 8; ++s) {
    const bf16x8 bc0 = (s & 1) ? bB0 : bA0;
    const bf16x8 bc1 = (s & 1) ? bB1 : bA1;
    if (s < 6) {  // refill the slot just consumed with s+2
      if (s & 1) { bB0 = BLOAD(s + 2, 0); bB1 = BLOAD(s + 2, 1); }
      else       { bA0 = BLOAD(s + 2, 0); bA1 = BLOAD(s + 2, 1); }
    }
    bf16x8 af[4];
#pragma unroll
    for (int mt = 0; mt < 4; ++mt) {
      const int row = mt * 16 + lrow;
      af[mt] = *(const bf16x8*)(ab + row * 512 + (((s * 4 + lhi) ^ (row & 7)) << 4));
    }
#pragma unroll
    for (int mt = 0; mt < 4; ++mt) {  // SWAPPED: D[o][m], lane regs = 4 contig o
      acc[mt][0] = __builtin_amdgcn_mfma_f32_16x16x32_bf16(bc0, af[mt], acc[mt][0], 0, 0, 0);
      acc[mt][1] = __builtin_amdgcn_mfma_f32_16x16x32_bf16(bc1, af[mt], acc[mt][1], 0, 0, 0);
    }
  }
#undef BLOAD

  // ---- LDS-bounce epilogue: 2 passes x 32 rows (reuses the 32KB A-LDS) ----
  // Write: acc[mt][oj]+bv at [rloc][c16 = wave*8+oj*4+lhi], slot c^(rloc&7)
  //        (8-beat optimal). Read: lane takes chunk lane^(rloc&7)
  //        (conflict-free permutation) -> ONE contiguous 1KB NT store/row.
#pragma unroll
  for (int pass = 0; pass < 2; ++pass) {
    asm volatile("s_waitcnt lgkmcnt(0)" ::: "memory");
    __builtin_amdgcn_s_barrier();
#pragma unroll
    for (int mt2 = 0; mt2 < 2; ++mt2) {
      const int mtg  = pass * 2 + mt2;
      const int rloc = mt2 * 16 + lrow;          // 0..31
#pragma unroll
      for (int oj = 0; oj < 2; ++oj) {
        const f32x4 v = acc[mtg][oj] + bv[oj];
        const int c = wave * 8 + oj * 4 + lhi;   // 16B chunk index 0..63
        *(f32x4*)(ab + rloc * 1024 + ((c ^ (rloc & 7)) << 4)) = v;
      }
    }
    asm volatile("s_waitcnt lgkmcnt(0)" ::: "memory");
    __builtin_amdgcn_s_barrier();
    // read + NT store: wave handles rows wave*4 .. +4 of this pass
#pragma unroll
    for (int j = 0; j < 4; ++j) {
      const int rloc = wave * 4 + j;
      const int m    = mbase + pass * 32 + rloc;
      const f32x4 v  = *(const f32x4*)(ab + rloc * 1024 + ((lane ^ (rloc & 7)) << 4));
      __builtin_nontemporal_store(
          v, (f32x4*)(out + ((size_t)m * NL + n) * DO_ + lane * 4));
    }
  }
}

// ---------------------------------------------------------------------------
// Fallback (only if ws too small for Wt): plain fp32, correct but slow.
// ---------------------------------------------------------------------------
__global__ __launch_bounds__(256) void nlinear_naive(
    const float* __restrict__ X, const float* __restrict__ W,
    const float* __restrict__ B, float* __restrict__ out) {
  const int n = blockIdx.y;
  const int m = blockIdx.x;
  const int o = threadIdx.x;
  __shared__ float xs[DK];
  xs[o] = X[((size_t)m * NL + n) * DK + o];
  __syncthreads();
  const float* Wn = W + (size_t)n * DK * DO_;
  float s = B[n * DO_ + o];
  for (int k = 0; k < DK; ++k) s = fmaf(xs[k], Wn[(size_t)k * DO_ + o], s);
  out[((size_t)m * NL + n) * DO_ + o] = s;
}

extern "C" void kernel_launch(void* const* d_in, const int* in_sizes, int n_in,
                              void* d_out, int out_size, void* d_ws, size_t ws_size,
                              hipStream_t stream) {
  const float* x = (const float*)d_in[0];
  const float* w = (const float*)d_in[1];
  const float* b = (const float*)d_in[2];
  float* out     = (float*)d_out;
  const size_t wt_bytes = (size_t)NL * DK * DO_ * sizeof(unsigned short);
  if (ws_size >= wt_bytes) {
    unsigned short* wt = (unsigned short*)d_ws;
    wt_prep<<<dim3(16, NL), 256, 0, stream>>>(w, wt);
    nlinear_mfma<<<dim3(2048), 512, 0, stream>>>(x, wt, b, out);
  } else {
    nlinear_naive<<<dim3(MB, NL), 256, 0, stream>>>(x, w, b, out);
  }
}

// Round 17
// 60.911 us; speedup vs baseline: 1.6254x; 1.1525x over previous
//
#include <hip/hip_runtime.h>
#include <hip/hip_bf16.h>

#define NL  128   // layers (n)
#define DK  256   // d_in (k)
#define DO_ 256   // d_out (o)
#define MB  1024  // batch (m)

typedef __attribute__((ext_vector_type(4))) float f32x4;
typedef __attribute__((ext_vector_type(8))) short bf16x8;
typedef __attribute__((ext_vector_type(8))) unsigned short u16x8;
typedef __attribute__((ext_vector_type(4))) unsigned short u16x4;

static __device__ __forceinline__ unsigned short f2bf(float f) {
  __hip_bfloat16 h = __float2bfloat16(f);
  return __builtin_bit_cast(unsigned short, h);
}

// ---------------------------------------------------------------------------
// Prep: W[n][k][o] fp32 -> Wt in MFMA B-fragment order, bf16 (verified R4-R16):
//   unit (o, kc[8-k chunk]) -> ob=o>>4, lrow=o&15, s=kc>>2, lhi=kc&3
//   elem offset = ((n*16+ob)*8 + s)*512 + (lhi*16+lrow)*8 + (k&7)
// so a wave's B-load for (ob, s) is ONE contiguous 1KB dwordx4 per lane.
// ---------------------------------------------------------------------------
__global__ __launch_bounds__(256) void wt_prep(const float* __restrict__ W,
                                               unsigned short* __restrict__ Wt) {
  const int n     = blockIdx.y;
  const int ktile = (blockIdx.x >> 2) * 64;
  const int otile = (blockIdx.x & 3) * 64;
  __shared__ float tile[64][65];  // +1 pad: conflict-free column reads
  const float* Wn = W + (size_t)n * DK * DO_;
  const int t  = threadIdx.x;
  const int lr = t >> 4;
  const int lc = (t & 15) * 4;
#pragma unroll
  for (int p = 0; p < 4; ++p) {
    const int k = p * 16 + lr;
    const float4 v = *(const float4*)(Wn + (size_t)(ktile + k) * DO_ + otile + lc);
    tile[k][lc + 0] = v.x; tile[k][lc + 1] = v.y;
    tile[k][lc + 2] = v.z; tile[k][lc + 3] = v.w;
  }
  __syncthreads();
  const int ol = t >> 2;            // local o 0..63
  const int o  = otile + ol;
  const int kq = t & 3;
  unsigned short* Wt_n = Wt + (size_t)n * DO_ * DK;
#pragma unroll
  for (int h = 0; h < 2; ++h) {
    u16x8 w;
#pragma unroll
    for (int j = 0; j < 8; ++j) w[j] = f2bf(tile[kq * 16 + h * 8 + j][ol]);
    const int kc = (ktile >> 3) + kq * 2 + h;   // global 8-k chunk id (0..31)
    const int ob = o >> 4, lrw = o & 15, s = kc >> 2, lh = kc & 3;
    *(u16x8*)(Wt_n + ((size_t)(ob * 8 + s) * 64 + lh * 16 + lrw) * 8) = w;
  }
}

// ---------------------------------------------------------------------------
// Main: R14/R16 structure with BM=32 so acc = 16 AGPRs and (512,8) fits the
// gfx950 UNIFIED 64-reg cap (16 AGPR + <=48 arch VGPR): 4 blocks/CU.
// Block = (n, 32 m-rows), 512 thr / 8 waves; wave = 32m x 32o (acc[2][2]).
// LDS 16KB: A-tile [32][256] bf16, reused by the 2-pass bounce epilogue.
// All verified pieces: swizzled stage (1KB coalesced row loads), prefrag Wt
// 2-deep B-pipe, swapped MFMA, LDS-bounce + full-line NT stores, XCD swizzle.
// ---------------------------------------------------------------------------
__global__ __launch_bounds__(512, 8) void nlinear_mfma(
    const float* __restrict__ X, const unsigned short* __restrict__ Wt,
    const float* __restrict__ bias, float* __restrict__ out) {
  const int wid  = blockIdx.x;
  const int n    = (wid & 7) * 16 + ((wid >> 3) & 15);
  const int mg   = wid >> 7;          // 0..31, 32 rows each
  const int t    = threadIdx.x;
  const int wave = t >> 6;            // 0..7 = o-slice of 32
  const int lane = t & 63;
  const int lrow = lane & 15;
  const int lhi  = lane >> 4;
  const int mbase = mg * 32;

  __shared__ unsigned short Alds[32 * 256];  // 16 KB; A-tile then bounce tile

  // ---- stage: wave w loads rows w*4+j (j=0..3), lane takes k=lane*4 ----
  const float* xw = X + ((size_t)(mbase + wave * 4) * NL + n) * DK + lane * 4;
  f32x4 xv[4];
#pragma unroll
  for (int j = 0; j < 4; ++j)
    xv[j] = *(const f32x4*)(xw + (size_t)j * NL * DK);

  char* ab = (char*)Alds;
#pragma unroll
  for (int j = 0; j < 4; ++j) {
    u16x4 h;
#pragma unroll
    for (int e = 0; e < 4; ++e) h[e] = f2bf(xv[j][e]);
    // row = wave*4+j; chunk c = lane>>1; slot = c ^ (row&7)  (verified)
    const int row = wave * 4 + j;
    *(u16x4*)(ab + row * 512 + (((lane >> 1) ^ (row & 7)) << 4) + (lane & 1) * 8) = h;
  }
  __syncthreads();  // staging barrier

  const unsigned short* Wn = Wt + (size_t)n * DO_ * DK;

  f32x4 acc[2][2];
#pragma unroll
  for (int mt = 0; mt < 2; ++mt)
#pragma unroll
    for (int oj = 0; oj < 2; ++oj) acc[mt][oj] = (f32x4){0.f, 0.f, 0.f, 0.f};

  // B-load helper: coalesced 1KB per instr from prefragmented, L2-resident Wt
#define BLOAD(s, oj) \
  (*(const bf16x8*)(Wn + ((size_t)(((wave * 2 + (oj)) * 8) + (s)) * 64 + lane) * 8))

  // 2-deep explicit B prefetch pipeline (all indices compile-time: no scratch)
  bf16x8 bA0 = BLOAD(0, 0), bA1 = BLOAD(0, 1);
  bf16x8 bB0 = BLOAD(1, 0), bB1 = BLOAD(1, 1);

#pragma unroll
  for (int s = 0; s < 8; ++s) {
    const bf16x8 bc0 = (s & 1) ? bB0 : bA0;
    const bf16x8 bc1 = (s & 1) ? bB1 : bA1;
    if (s < 6) {  // refill the slot just consumed with s+2
      if (s & 1) { bB0 = BLOAD(s + 2, 0); bB1 = BLOAD(s + 2, 1); }
      else       { bA0 = BLOAD(s + 2, 0); bA1 = BLOAD(s + 2, 1); }
    }
    bf16x8 af[2];
#pragma unroll
    for (int mt = 0; mt < 2; ++mt) {
      const int row = mt * 16 + lrow;
      af[mt] = *(const bf16x8*)(ab + row * 512 + (((s * 4 + lhi) ^ (row & 7)) << 4));
    }
#pragma unroll
    for (int mt = 0; mt < 2; ++mt) {  // SWAPPED: D[o][m], lane regs = 4 contig o
      acc[mt][0] = __builtin_amdgcn_mfma_f32_16x16x32_bf16(bc0, af[mt], acc[mt][0], 0, 0, 0);
      acc[mt][1] = __builtin_amdgcn_mfma_f32_16x16x32_bf16(bc1, af[mt], acc[mt][1], 0, 0, 0);
    }
  }
#undef BLOAD

  // bias (loaded late; epilogue LDS latency hides it)
  const float* bb = bias + n * DO_ + wave * 32 + lhi * 4;
  f32x4 bv[2];
#pragma unroll
  for (int oj = 0; oj < 2; ++oj) bv[oj] = *(const f32x4*)(bb + oj * 16);

  // ---- LDS-bounce epilogue: 2 passes x 16 rows (reuses the 16KB A-LDS) ----
  // Pass mt: write acc[mt][oj]+bv at [lrow][c16 = wave*8+oj*4+lhi],
  //          slot c^(lrow&7) (8-beat optimal). Read: wave rows wave*2..+2,
  //          lane chunk lane^(rloc&7) -> ONE contiguous 1KB NT store/row.
#pragma unroll
  for (int mt = 0; mt < 2; ++mt) {
    asm volatile("s_waitcnt lgkmcnt(0)" ::: "memory");
    __builtin_amdgcn_s_barrier();
#pragma unroll
    for (int oj = 0; oj < 2; ++oj) {
      const f32x4 v = acc[mt][oj] + bv[oj];
      const int c = wave * 8 + oj * 4 + lhi;   // 16B chunk index 0..63
      *(f32x4*)(ab + lrow * 1024 + ((c ^ (lrow & 7)) << 4)) = v;
    }
    asm volatile("s_waitcnt lgkmcnt(0)" ::: "memory");
    __builtin_amdgcn_s_barrier();
#pragma unroll
    for (int j = 0; j < 2; ++j) {
      const int rloc = wave * 2 + j;           // 0..15
      const int m    = mbase + mt * 16 + rloc;
      const f32x4 v  = *(const f32x4*)(ab + rloc * 1024 + ((lane ^ (rloc & 7)) << 4));
      __builtin_nontemporal_store(
          v, (f32x4*)(out + ((size_t)m * NL + n) * DO_ + lane * 4));
    }
  }
}

// ---------------------------------------------------------------------------
// Fallback (only if ws too small for Wt): plain fp32, correct but slow.
// ---------------------------------------------------------------------------
__global__ __launch_bounds__(256) void nlinear_naive(
    const float* __restrict__ X, const float* __restrict__ W,
    const float* __restrict__ B, float* __restrict__ out) {
  const int n = blockIdx.y;
  const int m = blockIdx.x;
  const int o = threadIdx.x;
  __shared__ float xs[DK];
  xs[o] = X[((size_t)m * NL + n) * DK + o];
  __syncthreads();
  const float* Wn = W + (size_t)n * DK * DO_;
  float s = B[n * DO_ + o];
  for (int k = 0; k < DK; ++k) s = fmaf(xs[k], Wn[(size_t)k * DO_ + o], s);
  out[((size_t)m * NL + n) * DO_ + o] = s;
}

extern "C" void kernel_launch(void* const* d_in, const int* in_sizes, int n_in,
                              void* d_out, int out_size, void* d_ws, size_t ws_size,
                              hipStream_t stream) {
  const float* x = (const float*)d_in[0];
  const float* w = (const float*)d_in[1];
  const float* b = (const float*)d_in[2];
  float* out     = (float*)d_out;
  const size_t wt_bytes = (size_t)NL * DK * DO_ * sizeof(unsigned short);
  if (ws_size >= wt_bytes) {
    unsigned short* wt = (unsigned short*)d_ws;
    wt_prep<<<dim3(16, NL), 256, 0, stream>>>(w, wt);
    nlinear_mfma<<<dim3(4096), 512, 0, stream>>>(x, wt, b, out);
  } else {
    nlinear_naive<<<dim3(MB, NL), 256, 0, stream>>>(x, w, b, out);
  }
}

// Round 18
// 58.695 us; speedup vs baseline: 1.6867x; 1.0377x over previous
//
#include <hip/hip_runtime.h>
#include <hip/hip_bf16.h>

#define NL  128   // layers (n)
#define DK  256   // d_in (k)
#define DO_ 256   // d_out (o)
#define MB  1024  // batch (m)

typedef __attribute__((ext_vector_type(4))) float f32x4;
typedef __attribute__((ext_vector_type(8))) short bf16x8;
typedef __attribute__((ext_vector_type(8))) unsigned short u16x8;
typedef __attribute__((ext_vector_type(4))) unsigned short u16x4;

static __device__ __forceinline__ unsigned short f2bf(float f) {
  __hip_bfloat16 h = __float2bfloat16(f);
  return __builtin_bit_cast(unsigned short, h);
}

// ---------------------------------------------------------------------------
// Prep: W[n][k][o] fp32 -> Wt in MFMA B-fragment order, bf16 (layout verified
// R4-R17):  elem (n,o,k): kc=k>>3, s=kc>>2, lh=kc&3, ob=o>>4, lrw=o&15 ->
//   offset = ((n*16+ob)*8 + s)*512 + (lh*16+lrw)*8 + (k&7)
// R18: output phase remapped so ONE WAVE writes ONE 1KB page (ob,s) with
// lane = lh*16+lrw -> dst = page + lane*16B: fully coalesced 1KB stores
// (was 4 scattered 256B spans per instr). LDS reads 2-way on pad-65 (free).
// ---------------------------------------------------------------------------
__global__ __launch_bounds__(256) void wt_prep(const float* __restrict__ W,
                                               unsigned short* __restrict__ Wt) {
  const int n     = blockIdx.y;
  const int ktile = (blockIdx.x >> 2) * 64;
  const int otile = (blockIdx.x & 3) * 64;
  __shared__ float tile[64][65];  // +1 pad: conflict-free column reads
  const float* Wn = W + (size_t)n * DK * DO_;
  const int t  = threadIdx.x;
  const int lr = t >> 4;
  const int lc = (t & 15) * 4;
#pragma unroll
  for (int p = 0; p < 4; ++p) {
    const int k = p * 16 + lr;
    const float4 v = *(const float4*)(Wn + (size_t)(ktile + k) * DO_ + otile + lc);
    tile[k][lc + 0] = v.x; tile[k][lc + 1] = v.y;
    tile[k][lc + 2] = v.z; tile[k][lc + 3] = v.w;
  }
  __syncthreads();
  // output: wave w, iter h -> page p = w*2+h of this 64x64 tile (8 pages)
  const int wv  = t >> 6;
  const int lane = t & 63;
  const int lh  = lane >> 4;        // k-subchunk within s
  const int lrw = lane & 15;        // o within ob
  unsigned short* Wt_n = Wt + (size_t)n * DO_ * DK;
#pragma unroll
  for (int h = 0; h < 2; ++h) {
    const int p      = wv * 2 + h;  // 0..7
    const int ob_loc = p & 3;
    const int s_loc  = p >> 2;
    const int ob = (otile >> 4) + ob_loc;
    const int s  = (ktile >> 5) + s_loc;
    u16x8 w;
#pragma unroll
    for (int j = 0; j < 8; ++j)
      w[j] = f2bf(tile[s_loc * 32 + lh * 8 + j][ob_loc * 16 + lrw]);
    // dst = page base + lane*16B  -> one contiguous 1KB store per wave
    *(u16x8*)(Wt_n + ((size_t)(ob * 8 + s) * 64 + lane) * 8) = w;
  }
}

// ---------------------------------------------------------------------------
// Main: EXACT R17 (best: 60.9 us, occupancy 72%, zero spill). Block = (n, 32
// m-rows), 512 thr / 8 waves; wave = 32m x 32o (acc[2][2] = 16 AGPR; fits the
// gfx950 unified 64-reg cap at (512,8) -> 4 blocks/CU). LDS 16KB: A-tile then
// bounce tile. Verified pieces: swizzled stage, prefrag Wt 2-deep B-pipe,
// swapped MFMA, LDS-bounce + full-line NT stores, XCD swizzle.
// ---------------------------------------------------------------------------
__global__ __launch_bounds__(512, 8) void nlinear_mfma(
    const float* __restrict__ X, const unsigned short* __restrict__ Wt,
    const float* __restrict__ bias, float* __restrict__ out) {
  const int wid  = blockIdx.x;
  const int n    = (wid & 7) * 16 + ((wid >> 3) & 15);
  const int mg   = wid >> 7;          // 0..31, 32 rows each
  const int t    = threadIdx.x;
  const int wave = t >> 6;            // 0..7 = o-slice of 32
  const int lane = t & 63;
  const int lrow = lane & 15;
  const int lhi  = lane >> 4;
  const int mbase = mg * 32;

  __shared__ unsigned short Alds[32 * 256];  // 16 KB; A-tile then bounce tile

  // ---- stage: wave w loads rows w*4+j (j=0..3), lane takes k=lane*4 ----
  const float* xw = X + ((size_t)(mbase + wave * 4) * NL + n) * DK + lane * 4;
  f32x4 xv[4];
#pragma unroll
  for (int j = 0; j < 4; ++j)
    xv[j] = *(const f32x4*)(xw + (size_t)j * NL * DK);

  char* ab = (char*)Alds;
#pragma unroll
  for (int j = 0; j < 4; ++j) {
    u16x4 h;
#pragma unroll
    for (int e = 0; e < 4; ++e) h[e] = f2bf(xv[j][e]);
    // row = wave*4+j; chunk c = lane>>1; slot = c ^ (row&7)  (verified)
    const int row = wave * 4 + j;
    *(u16x4*)(ab + row * 512 + (((lane >> 1) ^ (row & 7)) << 4) + (lane & 1) * 8) = h;
  }
  __syncthreads();  // staging barrier

  const unsigned short* Wn = Wt + (size_t)n * DO_ * DK;

  f32x4 acc[2][2];
#pragma unroll
  for (int mt = 0; mt < 2; ++mt)
#pragma unroll
    for (int oj = 0; oj < 2; ++oj) acc[mt][oj] = (f32x4){0.f, 0.f, 0.f, 0.f};

  // B-load helper: coalesced 1KB per instr from prefragmented, L2-resident Wt
#define BLOAD(s, oj) \
  (*(const bf16x8*)(Wn + ((size_t)(((wave * 2 + (oj)) * 8) + (s)) * 64 + lane) * 8))

  // 2-deep explicit B prefetch pipeline (all indices compile-time: no scratch)
  bf16x8 bA0 = BLOAD(0, 0), bA1 = BLOAD(0, 1);
  bf16x8 bB0 = BLOAD(1, 0), bB1 = BLOAD(1, 1);

#pragma unroll
  for (int s = 0; s < 8; ++s) {
    const bf16x8 bc0 = (s & 1) ? bB0 : bA0;
    const bf16x8 bc1 = (s & 1) ? bB1 : bA1;
    if (s < 6) {  // refill the slot just consumed with s+2
      if (s & 1) { bB0 = BLOAD(s + 2, 0); bB1 = BLOAD(s + 2, 1); }
      else       { bA0 = BLOAD(s + 2, 0); bA1 = BLOAD(s + 2, 1); }
    }
    bf16x8 af[2];
#pragma unroll
    for (int mt = 0; mt < 2; ++mt) {
      const int row = mt * 16 + lrow;
      af[mt] = *(const bf16x8*)(ab + row * 512 + (((s * 4 + lhi) ^ (row & 7)) << 4));
    }
#pragma unroll
    for (int mt = 0; mt < 2; ++mt) {  // SWAPPED: D[o][m], lane regs = 4 contig o
      acc[mt][0] = __builtin_amdgcn_mfma_f32_16x16x32_bf16(bc0, af[mt], acc[mt][0], 0, 0, 0);
      acc[mt][1] = __builtin_amdgcn_mfma_f32_16x16x32_bf16(bc1, af[mt], acc[mt][1], 0, 0, 0);
    }
  }
#undef BLOAD

  // bias (loaded late; epilogue LDS latency hides it)
  const float* bb = bias + n * DO_ + wave * 32 + lhi * 4;
  f32x4 bv[2];
#pragma unroll
  for (int oj = 0; oj < 2; ++oj) bv[oj] = *(const f32x4*)(bb + oj * 16);

  // ---- LDS-bounce epilogue: 2 passes x 16 rows (reuses the 16KB A-LDS) ----
  // Pass mt: write acc[mt][oj]+bv at [lrow][c16 = wave*8+oj*4+lhi],
  //          slot c^(lrow&7) (8-beat optimal). Read: wave rows wave*2..+2,
  //          lane chunk lane^(rloc&7) -> ONE contiguous 1KB NT store/row.
#pragma unroll
  for (int mt = 0; mt < 2; ++mt) {
    asm volatile("s_waitcnt lgkmcnt(0)" ::: "memory");
    __builtin_amdgcn_s_barrier();
#pragma unroll
    for (int oj = 0; oj < 2; ++oj) {
      const f32x4 v = acc[mt][oj] + bv[oj];
      const int c = wave * 8 + oj * 4 + lhi;   // 16B chunk index 0..63
      *(f32x4*)(ab + lrow * 1024 + ((c ^ (lrow & 7)) << 4)) = v;
    }
    asm volatile("s_waitcnt lgkmcnt(0)" ::: "memory");
    __builtin_amdgcn_s_barrier();
#pragma unroll
    for (int j = 0; j < 2; ++j) {
      const int rloc = wave * 2 + j;           // 0..15
      const int m    = mbase + mt * 16 + rloc;
      const f32x4 v  = *(const f32x4*)(ab + rloc * 1024 + ((lane ^ (rloc & 7)) << 4));
      __builtin_nontemporal_store(
          v, (f32x4*)(out + ((size_t)m * NL + n) * DO_ + lane * 4));
    }
  }
}

// ---------------------------------------------------------------------------
// Fallback (only if ws too small for Wt): plain fp32, correct but slow.
// ---------------------------------------------------------------------------
__global__ __launch_bounds__(256) void nlinear_naive(
    const float* __restrict__ X, const float* __restrict__ W,
    const float* __restrict__ B, float* __restrict__ out) {
  const int n = blockIdx.y;
  const int m = blockIdx.x;
  const int o = threadIdx.x;
  __shared__ float xs[DK];
  xs[o] = X[((size_t)m * NL + n) * DK + o];
  __syncthreads();
  const float* Wn = W + (size_t)n * DK * DO_;
  float s = B[n * DO_ + o];
  for (int k = 0; k < DK; ++k) s = fmaf(xs[k], Wn[(size_t)k * DO_ + o], s);
  out[((size_t)m * NL + n) * DO_ + o] = s;
}

extern "C" void kernel_launch(void* const* d_in, const int* in_sizes, int n_in,
                              void* d_out, int out_size, void* d_ws, size_t ws_size,
                              hipStream_t stream) {
  const float* x = (const float*)d_in[0];
  const float* w = (const float*)d_in[1];
  const float* b = (const float*)d_in[2];
  float* out     = (float*)d_out;
  const size_t wt_bytes = (size_t)NL * DK * DO_ * sizeof(unsigned short);
  if (ws_size >= wt_bytes) {
    unsigned short* wt = (unsigned short*)d_ws;
    wt_prep<<<dim3(16, NL), 256, 0, stream>>>(w, wt);
    nlinear_mfma<<<dim3(4096), 512, 0, stream>>>(x, wt, b, out);
  } else {
    nlinear_naive<<<dim3(MB, NL), 256, 0, stream>>>(x, w, b, out);
  }
}

// Round 19
// 58.294 us; speedup vs baseline: 1.6983x; 1.0069x over previous
//
#include <hip/hip_runtime.h>
#include <hip/hip_bf16.h>

#define NL  128   // layers (n)
#define DK  256   // d_in (k)
#define DO_ 256   // d_out (o)
#define MB  1024  // batch (m)

typedef __attribute__((ext_vector_type(4))) float f32x4;
typedef __attribute__((ext_vector_type(8))) short bf16x8;
typedef __attribute__((ext_vector_type(8))) unsigned short u16x8;
typedef __attribute__((ext_vector_type(4))) unsigned short u16x4;

static __device__ __forceinline__ unsigned short f2bf(float f) {
  __hip_bfloat16 h = __float2bfloat16(f);
  return __builtin_bit_cast(unsigned short, h);
}

// ---------------------------------------------------------------------------
// Prep: W[n][k][o] fp32 -> Wt in MFMA B-fragment order, bf16 (layout verified
// R4-R18). R18's coalesced output: one wave writes one 1KB page (ob,s),
// lane = lh*16+lrw -> dst = page + lane*16B. LDS reads 2-way on pad-65 (free).
// ---------------------------------------------------------------------------
__global__ __launch_bounds__(256) void wt_prep(const float* __restrict__ W,
                                               unsigned short* __restrict__ Wt) {
  const int n     = blockIdx.y;
  const int ktile = (blockIdx.x >> 2) * 64;
  const int otile = (blockIdx.x & 3) * 64;
  __shared__ float tile[64][65];  // +1 pad: conflict-free column reads
  const float* Wn = W + (size_t)n * DK * DO_;
  const int t  = threadIdx.x;
  const int lr = t >> 4;
  const int lc = (t & 15) * 4;
#pragma unroll
  for (int p = 0; p < 4; ++p) {
    const int k = p * 16 + lr;
    const float4 v = *(const float4*)(Wn + (size_t)(ktile + k) * DO_ + otile + lc);
    tile[k][lc + 0] = v.x; tile[k][lc + 1] = v.y;
    tile[k][lc + 2] = v.z; tile[k][lc + 3] = v.w;
  }
  __syncthreads();
  const int wv   = t >> 6;
  const int lane = t & 63;
  const int lh   = lane >> 4;        // k-subchunk within s
  const int lrw  = lane & 15;        // o within ob
  unsigned short* Wt_n = Wt + (size_t)n * DO_ * DK;
#pragma unroll
  for (int h = 0; h < 2; ++h) {
    const int p      = wv * 2 + h;   // page 0..7 of this 64x64 tile
    const int ob_loc = p & 3;
    const int s_loc  = p >> 2;
    const int ob = (otile >> 4) + ob_loc;
    const int s  = (ktile >> 5) + s_loc;
    u16x8 w;
#pragma unroll
    for (int j = 0; j < 8; ++j)
      w[j] = f2bf(tile[s_loc * 32 + lh * 8 + j][ob_loc * 16 + lrw]);
    *(u16x8*)(Wt_n + ((size_t)(ob * 8 + s) * 64 + lane) * 8) = w;
  }
}

// ---------------------------------------------------------------------------
// Main: R18 structure (58.7 us) + two harvest changes:
//  (1) SEPARATE 16KB bounce region (LDS 16+16=32KB, still 4 blocks/CU):
//      pass-0 epilogue writes need no pre-barrier (don't touch the A-tile)
//      -> 3 epilogue barriers instead of 4, writes overlap MFMA tails.
//  (2) 3-deep B prefetch pipeline (24 VGPR, covers full ~250cyc L2 latency;
//      unified file: 16 AGPR + ~40 VGPR <= 64-reg cap at (512,8), no spill).
// Block = (n, 32 m-rows), 512 thr / 8 waves; wave = 32m x 32o (acc[2][2]).
// All verified pieces: swizzled stage, prefrag Wt coalesced B-loads,
// swapped MFMA, LDS-bounce + full-line NT stores, XCD swizzle.
// ---------------------------------------------------------------------------
__global__ __launch_bounds__(512, 8) void nlinear_mfma(
    const float* __restrict__ X, const unsigned short* __restrict__ Wt,
    const float* __restrict__ bias, float* __restrict__ out) {
  const int wid  = blockIdx.x;
  const int n    = (wid & 7) * 16 + ((wid >> 3) & 15);
  const int mg   = wid >> 7;          // 0..31, 32 rows each
  const int t    = threadIdx.x;
  const int wave = t >> 6;            // 0..7 = o-slice of 32
  const int lane = t & 63;
  const int lrow = lane & 15;
  const int lhi  = lane >> 4;
  const int mbase = mg * 32;

  __shared__ unsigned short Alds[32 * 256];  // 16 KB A-tile
  __shared__ float Bnc[16 * 256];            // 16 KB bounce (separate region)

  // ---- stage: wave w loads rows w*4+j (j=0..3), lane takes k=lane*4 ----
  const float* xw = X + ((size_t)(mbase + wave * 4) * NL + n) * DK + lane * 4;
  f32x4 xv[4];
#pragma unroll
  for (int j = 0; j < 4; ++j)
    xv[j] = *(const f32x4*)(xw + (size_t)j * NL * DK);

  char* ab = (char*)Alds;
#pragma unroll
  for (int j = 0; j < 4; ++j) {
    u16x4 h;
#pragma unroll
    for (int e = 0; e < 4; ++e) h[e] = f2bf(xv[j][e]);
    // row = wave*4+j; chunk c = lane>>1; slot = c ^ (row&7)  (verified)
    const int row = wave * 4 + j;
    *(u16x4*)(ab + row * 512 + (((lane >> 1) ^ (row & 7)) << 4) + (lane & 1) * 8) = h;
  }
  __syncthreads();  // staging barrier

  const unsigned short* Wn = Wt + (size_t)n * DO_ * DK;

  f32x4 acc[2][2];
#pragma unroll
  for (int mt = 0; mt < 2; ++mt)
#pragma unroll
    for (int oj = 0; oj < 2; ++oj) acc[mt][oj] = (f32x4){0.f, 0.f, 0.f, 0.f};

  // B-load helper: coalesced 1KB per instr from prefragmented, L2-resident Wt
#define BLOAD(s, oj) \
  (*(const bf16x8*)(Wn + ((size_t)(((wave * 2 + (oj)) * 8) + (s)) * 64 + lane) * 8))

  // 3-deep explicit B prefetch pipeline (static indices; covers L2 latency)
  bf16x8 bP0 = BLOAD(0, 0), bP1 = BLOAD(0, 1);
  bf16x8 bQ0 = BLOAD(1, 0), bQ1 = BLOAD(1, 1);
  bf16x8 bR0 = BLOAD(2, 0), bR1 = BLOAD(2, 1);

#pragma unroll
  for (int s = 0; s < 8; ++s) {
    const int st = s % 3;  // s is unroll-constant -> fully static selection
    const bf16x8 bc0 = (st == 0) ? bP0 : (st == 1) ? bQ0 : bR0;
    const bf16x8 bc1 = (st == 0) ? bP1 : (st == 1) ? bQ1 : bR1;
    if (s < 5) {  // refill the stream just consumed with s+3
      if (st == 0)      { bP0 = BLOAD(s + 3, 0); bP1 = BLOAD(s + 3, 1); }
      else if (st == 1) { bQ0 = BLOAD(s + 3, 0); bQ1 = BLOAD(s + 3, 1); }
      else              { bR0 = BLOAD(s + 3, 0); bR1 = BLOAD(s + 3, 1); }
    }
    bf16x8 af[2];
#pragma unroll
    for (int mt = 0; mt < 2; ++mt) {
      const int row = mt * 16 + lrow;
      af[mt] = *(const bf16x8*)(ab + row * 512 + (((s * 4 + lhi) ^ (row & 7)) << 4));
    }
#pragma unroll
    for (int mt = 0; mt < 2; ++mt) {  // SWAPPED: D[o][m], lane regs = 4 contig o
      acc[mt][0] = __builtin_amdgcn_mfma_f32_16x16x32_bf16(bc0, af[mt], acc[mt][0], 0, 0, 0);
      acc[mt][1] = __builtin_amdgcn_mfma_f32_16x16x32_bf16(bc1, af[mt], acc[mt][1], 0, 0, 0);
    }
  }
#undef BLOAD

  // bias (loaded late; epilogue LDS latency hides it)
  const float* bb = bias + n * DO_ + wave * 32 + lhi * 4;
  f32x4 bv[2];
#pragma unroll
  for (int oj = 0; oj < 2; ++oj) bv[oj] = *(const f32x4*)(bb + oj * 16);

  // ---- bounce epilogue, separate region: 2 passes x 16 rows, 3 barriers ----
  // Write: acc[mt][oj]+bv at [lrow][c16 = wave*8+oj*4+lhi], slot c^(lrow&7)
  //        (2-way, free). Read: wave rows wave*2..+2, lane chunk
  //        lane^(rloc&7) (2-way, free) -> ONE contiguous 1KB NT store/row.
  char* bnc = (char*)Bnc;
#pragma unroll
  for (int mt = 0; mt < 2; ++mt) {
    // pass-0 writes need NO pre-barrier (fresh region); pass-1 needs WAR
    if (mt == 1) {
      asm volatile("s_waitcnt lgkmcnt(0)" ::: "memory");
      __builtin_amdgcn_s_barrier();
    }
#pragma unroll
    for (int oj = 0; oj < 2; ++oj) {
      const f32x4 v = acc[mt][oj] + bv[oj];
      const int c = wave * 8 + oj * 4 + lhi;   // 16B chunk index 0..63
      *(f32x4*)(bnc + lrow * 1024 + ((c ^ (lrow & 7)) << 4)) = v;
    }
    asm volatile("s_waitcnt lgkmcnt(0)" ::: "memory");
    __builtin_amdgcn_s_barrier();
#pragma unroll
    for (int j = 0; j < 2; ++j) {
      const int rloc = wave * 2 + j;           // 0..15
      const int m    = mbase + mt * 16 + rloc;
      const f32x4 v  = *(const f32x4*)(bnc + rloc * 1024 + ((lane ^ (rloc & 7)) << 4));
      __builtin_nontemporal_store(
          v, (f32x4*)(out + ((size_t)m * NL + n) * DO_ + lane * 4));
    }
  }
}

// ---------------------------------------------------------------------------
// Fallback (only if ws too small for Wt): plain fp32, correct but slow.
// ---------------------------------------------------------------------------
__global__ __launch_bounds__(256) void nlinear_naive(
    const float* __restrict__ X, const float* __restrict__ W,
    const float* __restrict__ B, float* __restrict__ out) {
  const int n = blockIdx.y;
  const int m = blockIdx.x;
  const int o = threadIdx.x;
  __shared__ float xs[DK];
  xs[o] = X[((size_t)m * NL + n) * DK + o];
  __syncthreads();
  const float* Wn = W + (size_t)n * DK * DO_;
  float s = B[n * DO_ + o];
  for (int k = 0; k < DK; ++k) s = fmaf(xs[k], Wn[(size_t)k * DO_ + o], s);
  out[((size_t)m * NL + n) * DO_ + o] = s;
}

extern "C" void kernel_launch(void* const* d_in, const int* in_sizes, int n_in,
                              void* d_out, int out_size, void* d_ws, size_t ws_size,
                              hipStream_t stream) {
  const float* x = (const float*)d_in[0];
  const float* w = (const float*)d_in[1];
  const float* b = (const float*)d_in[2];
  float* out     = (float*)d_out;
  const size_t wt_bytes = (size_t)NL * DK * DO_ * sizeof(unsigned short);
  if (ws_size >= wt_bytes) {
    unsigned short* wt = (unsigned short*)d_ws;
    wt_prep<<<dim3(16, NL), 256, 0, stream>>>(w, wt);
    nlinear_mfma<<<dim3(4096), 512, 0, stream>>>(x, wt, b, out);
  } else {
    nlinear_naive<<<dim3(MB, NL), 256, 0, stream>>>(x, w, b, out);
  }
}